// Round 11
// baseline (5018.064 us; speedup 1.0000x reference)
//
#include <hip/hip_runtime.h>
#include <hip/hip_bf16.h>

#define SEQ    256
#define BATCH  64
#define HID    1024
#define G4     4096
#define NWG    256
#define LDK    1032   // padded LDS row stride (bf16 elems): 2064B rows, 2-way bank alias only

typedef __bf16 bf16x8 __attribute__((ext_vector_type(8)));
typedef float  f32x4  __attribute__((ext_vector_type(4)));
typedef int    i32x4  __attribute__((ext_vector_type(4)));
typedef unsigned short u16;

__device__ __forceinline__ u16 f2bf(float f) {
    unsigned int u = __float_as_uint(f);
    unsigned int r = (u + 0x7fffu + ((u >> 16) & 1u)) >> 16;  // RNE
    return (u16)r;
}

__device__ __forceinline__ float sigmoid_f(float x) {
    x = fminf(fmaxf(x, -30.f), 30.f);
    return 1.f / (1.f + __expf(-x));
}
__device__ __forceinline__ float tanh_f(float x) {
    x = fminf(fmaxf(x, -15.f), 15.f);
    float e2 = __expf(2.f * x);
    return (e2 - 1.f) / (e2 + 1.f);
}

// ---- flag-array grid barrier: WG wg sc-stores flags[wg]=fid (no RMW chain);
// wave 0 polls all 256 flags, 4 per lane via one dwordx4 sc-load. Monotonic fids.
__device__ __forceinline__ void bar_arrive(int* flags, int wg, int fid) {
    asm volatile("s_waitcnt vmcnt(0)" ::: "memory");  // h sc-store visible at L3
    __syncthreads();                                  // whole WG drained
    if (threadIdx.x == 0)
        __hip_atomic_store(flags + wg, fid, __ATOMIC_RELAXED, __HIP_MEMORY_SCOPE_AGENT);
}

__device__ __forceinline__ void bar_wait(const int* flags, int fid) {
    if (threadIdx.x < 64) {
        const int* p = flags + threadIdx.x * 4;
        for (;;) {
            i32x4 v;
            asm volatile("global_load_dwordx4 %0, %1, off sc0 sc1"
                         : "=v"(v) : "v"(p));
            asm volatile("s_waitcnt vmcnt(0)" ::: "memory");
            if (__all(v[0] >= fid && v[1] >= fid && v[2] >= fid && v[3] >= fid)) break;
        }
    }
    __syncthreads();
}

// heavy barrier: full L2 writeback/invalidate around it (layer boundaries only)
__device__ __forceinline__ void bar_heavy(int* flags, int wg, int fid) {
    if (threadIdx.x == 0) __threadfence();   // release: wbl2 dirty Y0/hbuf-init lines
    bar_arrive(flags, wg, fid);
    bar_wait(flags, fid);
    if (threadIdx.x == 0) __threadfence();   // acquire: inv stale L1/L2 copies
    __syncthreads();
}

// ---------------- fp32 -> bf16 conversion (x) + barrier-state init ----------------
__global__ void cvt_f32_bf16(const float* __restrict__ in, u16* __restrict__ out, int n4,
                             int* __restrict__ bar) {
    int idx = blockIdx.x * blockDim.x + threadIdx.x;
    if (idx < 1024)
        __hip_atomic_store(bar + idx, 0, __ATOMIC_RELAXED, __HIP_MEMORY_SCOPE_AGENT);
    int stride = gridDim.x * blockDim.x;
    const float4* in4 = (const float4*)in;
    ushort4* out4 = (ushort4*)out;
    for (int i = idx; i < n4; i += stride) {
        float4 v = in4[i];
        ushort4 o;
        o.x = f2bf(v.x); o.y = f2bf(v.y); o.z = f2bf(v.z); o.w = f2bf(v.w);
        out4[i] = o;
    }
}

// x-GEMM for one step: A from global (L2-cached), B from LDS. 32 MFMAs.
__device__ __forceinline__ f32x4 xgemm(const u16* __restrict__ A0, const u16* B0) {
    f32x4 acc = {0.f, 0.f, 0.f, 0.f};
    #pragma unroll 8
    for (int ks = 0; ks < 32; ++ks) {
        bf16x8 a = *(const bf16x8*)(A0 + ks * 32);
        bf16x8 b = *(const bf16x8*)(B0 + ks * 32);
        acc = __builtin_amdgcn_mfma_f32_16x16x32_bf16(a, b, acc, 0, 0, 0);
    }
    return acc;
}

// issue one coherent (L2-bypassing) 16B h-frag load at byte offset OFFS
#define LDH(k, OFFS) \
    asm volatile("global_load_dwordx4 %0, %1, off offset:" OFFS " sc0 sc1" \
                 : "=v"(hf[k]) : "v"(A1))

// ---------------- persistent cooperative LSTM ----------------
// WG w owns h-columns [4w, 4w+4). Local gate row j = gate*4 + col (0..15).
// Wave v handles batch rows [16v, 16v+16).
__global__ void __launch_bounds__(256, 1) lstm_coop(
    const u16* Xbf,               // [SEQ][BATCH][HID] bf16
    u16* Y0bf,                    // [SEQ][BATCH][HID] bf16 (layer-0 outputs)
    u16* __restrict__ hbuf,       // [2][BATCH][HID] bf16 (double-buffered h)
    int* __restrict__ bar,        // flag array [256]
    const float* __restrict__ h0,
    const float* __restrict__ c0,
    const float* __restrict__ Wx, // [2][4096][1024]
    const float* __restrict__ bx,
    const float* __restrict__ Wh, // [2][4096][1024]
    const float* __restrict__ bh,
    float* __restrict__ out)      // ys | hT | cT
{
    __shared__ u16   WxL[16 * LDK];
    __shared__ u16   WhL[16 * LDK];
    __shared__ float biasL[16];
    __shared__ float gbuf[4][16][17];

    const int wg   = blockIdx.x;
    const int hc0  = wg * 4;
    const int tid  = threadIdx.x;
    const int wv   = tid >> 6;
    const int lane = tid & 63;
    const int fr   = lane & 15;
    const int fg   = lane >> 4;
    const int bl   = lane >> 2;
    const int col  = lane & 3;
    const int b_cell = wv * 16 + bl;

    int bar_id = 0;

    float* ys = out;
    float* hT = out + (size_t)SEQ * BATCH * HID;
    float* cT = hT + (size_t)2 * BATCH * HID;

    for (int layer = 0; layer < 2; ++layer) {
        for (int j = 0; j < 16; ++j) {
            int gate = j >> 2, jc = j & 3;
            size_t row = (size_t)layer * G4 + (size_t)gate * HID + hc0 + jc;
            const float4* sx = (const float4*)(Wx + row * HID);
            const float4* sh = (const float4*)(Wh + row * HID);
            float4 vx = sx[tid];
            float4 vh = sh[tid];
            ushort4 ox, oh;
            ox.x = f2bf(vx.x); ox.y = f2bf(vx.y); ox.z = f2bf(vx.z); ox.w = f2bf(vx.w);
            oh.x = f2bf(vh.x); oh.y = f2bf(vh.y); oh.z = f2bf(vh.z); oh.w = f2bf(vh.w);
            *(ushort4*)&WxL[j * LDK + tid * 4] = ox;
            *(ushort4*)&WhL[j * LDK + tid * 4] = oh;
        }
        if (tid < 16) {
            int gate = tid >> 2, jc = tid & 3;
            int row = layer * G4 + gate * HID + hc0 + jc;
            biasL[tid] = bx[row] + bh[row];
        }
        {
            int b = tid >> 2, cc = tid & 3;
            float hv = h0[(size_t)layer * BATCH * HID + (size_t)b * HID + hc0 + cc];
            hbuf[(size_t)b * HID + hc0 + cc] = f2bf(hv);   // buffer 0 (published by heavy bar)
        }
        float c_reg = c0[(size_t)layer * BATCH * HID + (size_t)b_cell * HID + hc0 + col];
        bar_heavy(bar, wg, ++bar_id);   // publish hbuf init (+ Y0 from prev layer)

        const u16* Xsrc = (layer == 0) ? Xbf : Y0bf;
        const u16* B0 = &WxL[fr * LDK + fg * 8];
        const u16* B1 = &WhL[fr * LDK + fg * 8];
        const size_t arow = (size_t)(wv * 16 + fr) * HID + fg * 8;
        int cur = 0;
        float h_out = 0.f;

        // prologue: x-GEMM for t=0
        f32x4 accx = xgemm(Xsrc + arow, B0);

        for (int t = 0; t < SEQ; ++t) {
            // ---- h GEMM: issue all 32 coherent loads, one wait, 4 independent chains ----
            const u16* A1 = hbuf + (size_t)cur * BATCH * HID + arow;
            bf16x8 hf[32];
            LDH( 0,    "0"); LDH( 1,   "64"); LDH( 2,  "128"); LDH( 3,  "192");
            LDH( 4,  "256"); LDH( 5,  "320"); LDH( 6,  "384"); LDH( 7,  "448");
            LDH( 8,  "512"); LDH( 9,  "576"); LDH(10,  "640"); LDH(11,  "704");
            LDH(12,  "768"); LDH(13,  "832"); LDH(14,  "896"); LDH(15,  "960");
            LDH(16, "1024"); LDH(17, "1088"); LDH(18, "1152"); LDH(19, "1216");
            LDH(20, "1280"); LDH(21, "1344"); LDH(22, "1408"); LDH(23, "1472");
            LDH(24, "1536"); LDH(25, "1600"); LDH(26, "1664"); LDH(27, "1728");
            LDH(28, "1792"); LDH(29, "1856"); LDH(30, "1920"); LDH(31, "1984");
            asm volatile("s_waitcnt vmcnt(0)" ::: "memory");
            __builtin_amdgcn_sched_barrier(0);
            f32x4 acc0 = accx;
            f32x4 acc1 = {0.f, 0.f, 0.f, 0.f};
            f32x4 acc2 = {0.f, 0.f, 0.f, 0.f};
            f32x4 acc3 = {0.f, 0.f, 0.f, 0.f};
            #pragma unroll
            for (int ks = 0; ks < 32; ks += 4) {
                acc0 = __builtin_amdgcn_mfma_f32_16x16x32_bf16(hf[ks],     *(const bf16x8*)(B1 + ks * 32),       acc0, 0, 0, 0);
                acc1 = __builtin_amdgcn_mfma_f32_16x16x32_bf16(hf[ks + 1], *(const bf16x8*)(B1 + (ks + 1) * 32), acc1, 0, 0, 0);
                acc2 = __builtin_amdgcn_mfma_f32_16x16x32_bf16(hf[ks + 2], *(const bf16x8*)(B1 + (ks + 2) * 32), acc2, 0, 0, 0);
                acc3 = __builtin_amdgcn_mfma_f32_16x16x32_bf16(hf[ks + 3], *(const bf16x8*)(B1 + (ks + 3) * 32), acc3, 0, 0, 0);
            }

            float bias = biasL[fr];
            gbuf[wv][fg * 4 + 0][fr] = acc0[0] + acc1[0] + acc2[0] + acc3[0] + bias;
            gbuf[wv][fg * 4 + 1][fr] = acc0[1] + acc1[1] + acc2[1] + acc3[1] + bias;
            gbuf[wv][fg * 4 + 2][fr] = acc0[2] + acc1[2] + acc2[2] + acc3[2] + bias;
            gbuf[wv][fg * 4 + 3][fr] = acc0[3] + acc1[3] + acc2[3] + acc3[3] + bias;
            float gi = gbuf[wv][bl][0 + col];
            float gf = gbuf[wv][bl][4 + col];
            float gg = gbuf[wv][bl][8 + col];
            float go = gbuf[wv][bl][12 + col];

            c_reg = sigmoid_f(gf) * c_reg + sigmoid_f(gi) * tanh_f(gg);
            h_out = sigmoid_f(go) * tanh_f(c_reg);

            u16 hb = f2bf(h_out);
            {   // coherent write-through h store (visible at L3 to all XCDs)
                u16* hdst = hbuf + (size_t)(cur ^ 1) * BATCH * HID + (size_t)b_cell * HID + hc0 + col;
                unsigned int hv32 = hb;
                asm volatile("global_store_short %0, %1, off sc0 sc1"
                             :: "v"(hdst), "v"(hv32) : "memory");
            }

            // ---- arrive first (drains only the h store), then outputs + x-prefetch ----
            int tgt = ++bar_id;
            bar_arrive(bar, wg, tgt);
            if (layer == 0) {
                Y0bf[(size_t)t * BATCH * HID + (size_t)b_cell * HID + hc0 + col] = hb;
            } else {
                ys[(size_t)t * BATCH * HID + (size_t)b_cell * HID + hc0 + col] = h_out;
            }
            int tn = (t + 1) & 255;
            f32x4 acc2n = xgemm(Xsrc + (size_t)tn * BATCH * HID + arow, B0);
            bar_wait(bar, tgt);
            accx = acc2n;
            cur ^= 1;
        }

        hT[(size_t)layer * BATCH * HID + (size_t)b_cell * HID + hc0 + col] = h_out;
        cT[(size_t)layer * BATCH * HID + (size_t)b_cell * HID + hc0 + col] = c_reg;

        bar_heavy(bar, wg, ++bar_id);   // publish Y0 before next layer reads it
    }
}

extern "C" void kernel_launch(void* const* d_in, const int* in_sizes, int n_in,
                              void* d_out, int out_size, void* d_ws, size_t ws_size,
                              hipStream_t stream) {
    const float* x  = (const float*)d_in[0];
    const float* h0 = (const float*)d_in[1];
    const float* c0 = (const float*)d_in[2];
    const float* Wx = (const float*)d_in[3];
    const float* bx = (const float*)d_in[4];
    const float* Wh = (const float*)d_in[5];
    const float* bh = (const float*)d_in[6];
    float* out = (float*)d_out;

    u16* Xbf  = (u16*)d_ws;
    u16* Y0bf = Xbf + (size_t)SEQ * BATCH * HID;
    u16* hbuf = Y0bf + (size_t)SEQ * BATCH * HID;
    int* bar  = (int*)(hbuf + (size_t)2 * BATCH * HID);

    int n4 = (SEQ * BATCH * HID) / 4;
    cvt_f32_bf16<<<dim3(1024), dim3(256), 0, stream>>>(x, Xbf, n4, bar);

    void* args[] = {(void*)&Xbf, (void*)&Y0bf, (void*)&hbuf, (void*)&bar,
                    (void*)&h0, (void*)&c0, (void*)&Wx, (void*)&bx,
                    (void*)&Wh, (void*)&bh, (void*)&out};
    hipLaunchCooperativeKernel((void*)lstm_coop, dim3(NWG), dim3(256), args, 0, stream);
}

// Round 12
// 3032.243 us; speedup vs baseline: 1.6549x; 1.6549x over previous
//
#include <hip/hip_runtime.h>
#include <hip/hip_bf16.h>

#define SEQ    256
#define BATCH  64
#define HID    1024
#define G4     4096
#define NWG    256
#define NTH    256
#define LDK2   1032   // padded LDS row stride (bf16): 2064B rows

typedef __bf16 bf16x8 __attribute__((ext_vector_type(8)));
typedef float  f32x4  __attribute__((ext_vector_type(4)));
typedef int    i32x2  __attribute__((ext_vector_type(2)));
typedef unsigned short u16;

__device__ __forceinline__ u16 f2bf(float f) {
    unsigned int u = __float_as_uint(f);
    unsigned int r = (u + 0x7fffu + ((u >> 16) & 1u)) >> 16;  // RNE
    return (u16)r;
}
__device__ __forceinline__ float sigmoid_f(float x) {
    x = fminf(fmaxf(x, -30.f), 30.f);
    return 1.f / (1.f + __expf(-x));
}
__device__ __forceinline__ float tanh_f(float x) {
    x = fminf(fmaxf(x, -15.f), 15.f);
    float e2 = __expf(2.f * x);
    return (e2 - 1.f) / (e2 + 1.f);
}

// ---------------- prep: fp32->bf16 for x; zero flags ----------------
__global__ void cvt_f32_bf16(const float* __restrict__ in, u16* __restrict__ out, int n4,
                             int* __restrict__ bar) {
    int idx = blockIdx.x * blockDim.x + threadIdx.x;
    if (idx < 1024)
        __hip_atomic_store(bar + idx, 0, __ATOMIC_RELAXED, __HIP_MEMORY_SCOPE_AGENT);
    int stride = gridDim.x * blockDim.x;
    const float4* in4 = (const float4*)in;
    ushort4* out4 = (ushort4*)out;
    for (int i = idx; i < n4; i += stride) {
        float4 v = in4[i];
        ushort4 o;
        o.x = f2bf(v.x); o.y = f2bf(v.y); o.z = f2bf(v.z); o.w = f2bf(v.w);
        out4[i] = o;
    }
}

// ---- domain flag barrier (128 WGs/domain). Signal: sc-store own flag.
// Wait: wave 0 polls 128 flags, 2 per lane, via sc dwordx2. Monotonic fids.
__device__ __forceinline__ void bar_signal(int* f, int idx, int fid) {
    asm volatile("s_waitcnt vmcnt(0)" ::: "memory");  // drain h/Y0 sc-stores to L3
    __syncthreads();                                  // whole WG drained
    if (threadIdx.x == 0)
        __hip_atomic_store(f + idx, fid, __ATOMIC_RELAXED, __HIP_MEMORY_SCOPE_AGENT);
}
__device__ __forceinline__ void bar_wait128(const int* f, int fid) {
    if (threadIdx.x < 64) {
        const int* p = f + threadIdx.x * 2;
        for (;;) {
            i32x2 v;
            asm volatile("global_load_dwordx2 %0, %1, off sc0 sc1" : "=v"(v) : "v"(p));
            asm volatile("s_waitcnt vmcnt(0)" ::: "memory");
            if (__all(v[0] >= fid && v[1] >= fid)) break;
        }
    }
    __syncthreads();
}

#define SCLD(dst, base, OFFS) \
    asm volatile("global_load_dwordx4 %0, %1, off offset:" OFFS " sc0 sc1" \
                 : "=v"(dst) : "v"(base))
#define SCLD32(a, base) do { \
    SCLD(a[ 0],base,   "0"); SCLD(a[ 1],base,  "64"); SCLD(a[ 2],base, "128"); SCLD(a[ 3],base, "192"); \
    SCLD(a[ 4],base, "256"); SCLD(a[ 5],base, "320"); SCLD(a[ 6],base, "384"); SCLD(a[ 7],base, "448"); \
    SCLD(a[ 8],base, "512"); SCLD(a[ 9],base, "576"); SCLD(a[10],base, "640"); SCLD(a[11],base, "704"); \
    SCLD(a[12],base, "768"); SCLD(a[13],base, "832"); SCLD(a[14],base, "896"); SCLD(a[15],base, "960"); \
    SCLD(a[16],base,"1024"); SCLD(a[17],base,"1088"); SCLD(a[18],base,"1152"); SCLD(a[19],base,"1216"); \
    SCLD(a[20],base,"1280"); SCLD(a[21],base,"1344"); SCLD(a[22],base,"1408"); SCLD(a[23],base,"1472"); \
    SCLD(a[24],base,"1536"); SCLD(a[25],base,"1600"); SCLD(a[26],base,"1664"); SCLD(a[27],base,"1728"); \
    SCLD(a[28],base,"1792"); SCLD(a[29],base,"1856"); SCLD(a[30],base,"1920"); SCLD(a[31],base,"1984"); \
} while (0)

// 2-N-tile x-GEMM: A plain (L2), B from LDS. One A-fragment feeds both tiles.
__device__ __forceinline__ void xgemm2_plain(const u16* __restrict__ A,
                                             const u16* Ba, const u16* Bb,
                                             f32x4& r0, f32x4& r1) {
    f32x4 a0 = {0.f,0.f,0.f,0.f}, a1 = {0.f,0.f,0.f,0.f};
    #pragma unroll
    for (int ks = 0; ks < 32; ++ks) {
        bf16x8 a = *(const bf16x8*)(A + ks * 32);
        a0 = __builtin_amdgcn_mfma_f32_16x16x32_bf16(a, *(const bf16x8*)(Ba + ks * 32), a0, 0, 0, 0);
        a1 = __builtin_amdgcn_mfma_f32_16x16x32_bf16(a, *(const bf16x8*)(Bb + ks * 32), a1, 0, 0, 0);
    }
    r0 = a0; r1 = a1;
}
// 2-N-tile x-GEMM with sc-loaded A (Y0 cross-XCD)
__device__ __forceinline__ void xgemm2_sc(const u16* A, const u16* Ba, const u16* Bb,
                                          f32x4& r0, f32x4& r1) {
    bf16x8 xf[32];
    SCLD32(xf, A);
    asm volatile("s_waitcnt vmcnt(0)" ::: "memory");
    __builtin_amdgcn_sched_barrier(0);
    f32x4 a0 = {0.f,0.f,0.f,0.f}, a1 = {0.f,0.f,0.f,0.f};
    #pragma unroll
    for (int ks = 0; ks < 32; ++ks) {
        a0 = __builtin_amdgcn_mfma_f32_16x16x32_bf16(xf[ks], *(const bf16x8*)(Ba + ks * 32), a0, 0, 0, 0);
        a1 = __builtin_amdgcn_mfma_f32_16x16x32_bf16(xf[ks], *(const bf16x8*)(Bb + ks * 32), a1, 0, 0, 0);
    }
    r0 = a0; r1 = a1;
}

// ---------------- layer-pipelined persistent LSTM ----------------
// role = wg>>7 (layer); wl = wg&127 owns h-cols [8wl, 8wl+8) x 4 gates = 32 gate-rows.
// Wave wv: batch rows [16wv,16wv+16) x all 32 gate-cols (2 MFMA tiles, shared A-frag).
// Cell: thread tid -> row b = tid>>2, cols (tid&3) and (tid&3)+4.
// L1 lags L0 one step; polls L0's flags before sc-loading Y0(t+1). No back-pressure.
__global__ void __launch_bounds__(NTH, 1) lstm_coop(
    const u16* __restrict__ Xbf,   // [SEQ][BATCH][HID] bf16
    u16* __restrict__ Y0bf,        // [SEQ][BATCH][HID] bf16 (L0 out, sc both sides)
    u16* __restrict__ hbuf,        // [2 roles][2][BATCH][HID] bf16 (sc-accessed)
    int* __restrict__ bar,         // fa[128] | fb[128]
    const float* __restrict__ h0,
    const float* __restrict__ c0,
    const float* __restrict__ Wx,  // [2][4096][1024] fp32
    const float* __restrict__ bx,
    const float* __restrict__ Wh,  // [2][4096][1024] fp32
    const float* __restrict__ bh,
    float* __restrict__ out)       // ys | hT | cT
{
    __shared__ u16   WxL[32 * LDK2];
    __shared__ u16   WhL[32 * LDK2];
    __shared__ float biasL[32];
    __shared__ float gbuf[4][16][33];   // [wave][local row][gate-col j 0..31], padded

    const int wg   = blockIdx.x;
    const int role = wg >> 7;
    const int wl   = wg & 127;
    const int hc0  = wl * 8;
    const int tid  = threadIdx.x;
    const int wv   = tid >> 6;
    const int lane = tid & 63;
    const int fr   = lane & 15;
    const int fg   = lane >> 4;
    const int b_c  = tid >> 2;       // cell batch row 0..63
    const int c2   = tid & 3;        // cell cols c2, c2+4

    int* fa = bar;
    int* fb = bar + 128;
    int* ownf = role ? fb : fa;

    u16* hbufR = hbuf + (size_t)role * 2 * BATCH * HID;

    float* ys = out;
    float* hT = out + (size_t)SEQ * BATCH * HID;
    float* cT = hT + (size_t)2 * BATCH * HID;

    // ---- stage Wx/Wh slices (32 gate-rows each) into LDS, fp32->bf16 ----
    for (int j = 0; j < 32; ++j) {
        int gate = j >> 3, jc = j & 7;
        size_t row = (size_t)role * G4 + (size_t)gate * HID + hc0 + jc;
        float4 vx = ((const float4*)(Wx + row * HID))[tid];
        float4 vh = ((const float4*)(Wh + row * HID))[tid];
        ushort4 ox, oh;
        ox.x = f2bf(vx.x); ox.y = f2bf(vx.y); ox.z = f2bf(vx.z); ox.w = f2bf(vx.w);
        oh.x = f2bf(vh.x); oh.y = f2bf(vh.y); oh.z = f2bf(vh.z); oh.w = f2bf(vh.w);
        *(ushort4*)&WxL[j * LDK2 + tid * 4] = ox;
        *(ushort4*)&WhL[j * LDK2 + tid * 4] = oh;
    }
    if (tid < 32) {
        int gate = tid >> 3, jc = tid & 7;
        int row = role * G4 + gate * HID + hc0 + jc;
        biasL[tid] = bx[row] + bh[row];
    }

    // ---- init h (sc-stores, buffer 0) and per-thread c (2 cells) ----
    float c_reg0, c_reg1;
    {
        float hv0 = h0[(size_t)role * BATCH * HID + (size_t)b_c * HID + hc0 + c2];
        float hv1 = h0[(size_t)role * BATCH * HID + (size_t)b_c * HID + hc0 + c2 + 4];
        u16* d0 = hbufR + (size_t)b_c * HID + hc0 + c2;
        u16* d1 = d0 + 4;
        unsigned int v0 = f2bf(hv0), v1 = f2bf(hv1);
        asm volatile("global_store_short %0, %1, off sc0 sc1" :: "v"(d0), "v"(v0) : "memory");
        asm volatile("global_store_short %0, %1, off sc0 sc1" :: "v"(d1), "v"(v1) : "memory");
        c_reg0 = c0[(size_t)role * BATCH * HID + (size_t)b_c * HID + hc0 + c2];
        c_reg1 = c0[(size_t)role * BATCH * HID + (size_t)b_c * HID + hc0 + c2 + 4];
    }

    bar_signal(ownf, wl, 1);
    bar_wait128(ownf, 1);

    const u16* B0a = &WxL[fr * LDK2 + fg * 8];
    const u16* B0b = &WxL[(16 + fr) * LDK2 + fg * 8];
    const u16* B1a = &WhL[fr * LDK2 + fg * 8];
    const u16* B1b = &WhL[(16 + fr) * LDK2 + fg * 8];
    const size_t arow = (size_t)(wv * 16 + fr) * HID + fg * 8;
    const float bias0 = biasL[fr];
    const float bias1 = biasL[16 + fr];

    f32x4 ax0, ax1;
    if (role == 0) {
        xgemm2_plain(Xbf + arow, B0a, B0b, ax0, ax1);
    } else {
        bar_wait128(fa, 2);                       // Y0(0) published
        xgemm2_sc(Y0bf + arow, B0a, B0b, ax0, ax1);
    }

    int cur = 0;
    float h_out0 = 0.f, h_out1 = 0.f;

    for (int t = 0; t < SEQ; ++t) {
        // ---- h-GEMM: 32 sc-loads (one A-frag), 2 B-chains, 64 MFMAs ----
        const u16* A1 = hbufR + (size_t)cur * BATCH * HID + arow;
        bf16x8 hf[32];
        SCLD32(hf, A1);
        asm volatile("s_waitcnt vmcnt(0)" ::: "memory");
        __builtin_amdgcn_sched_barrier(0);
        f32x4 acc0 = ax0, acc1 = ax1;
        #pragma unroll
        for (int ks = 0; ks < 32; ++ks) {
            bf16x8 a = hf[ks];
            acc0 = __builtin_amdgcn_mfma_f32_16x16x32_bf16(a, *(const bf16x8*)(B1a + ks * 32), acc0, 0, 0, 0);
            acc1 = __builtin_amdgcn_mfma_f32_16x16x32_bf16(a, *(const bf16x8*)(B1b + ks * 32), acc1, 0, 0, 0);
        }

        // ---- gates -> gbuf ----
        #pragma unroll
        for (int i = 0; i < 4; ++i) {
            gbuf[wv][fg * 4 + i][fr]      = acc0[i] + bias0;
            gbuf[wv][fg * 4 + i][16 + fr] = acc1[i] + bias1;
        }
        __syncthreads();

        // ---- cell update (2 cells/thread) ----
        const int bw = b_c >> 4, br = b_c & 15;
        float gi0 = gbuf[bw][br][c2];          float gi1 = gbuf[bw][br][c2 + 4];
        float gf0 = gbuf[bw][br][8 + c2];      float gf1 = gbuf[bw][br][8 + c2 + 4];
        float gg0 = gbuf[bw][br][16 + c2];     float gg1 = gbuf[bw][br][16 + c2 + 4];
        float go0 = gbuf[bw][br][24 + c2];     float go1 = gbuf[bw][br][24 + c2 + 4];
        c_reg0 = sigmoid_f(gf0) * c_reg0 + sigmoid_f(gi0) * tanh_f(gg0);
        h_out0 = sigmoid_f(go0) * tanh_f(c_reg0);
        c_reg1 = sigmoid_f(gf1) * c_reg1 + sigmoid_f(gi1) * tanh_f(gg1);
        h_out1 = sigmoid_f(go1) * tanh_f(c_reg1);

        unsigned int hb0 = f2bf(h_out0), hb1 = f2bf(h_out1);
        {   // h(t+1) sc-stores
            u16* d0 = hbufR + (size_t)(cur ^ 1) * BATCH * HID + (size_t)b_c * HID + hc0 + c2;
            u16* d1 = d0 + 4;
            asm volatile("global_store_short %0, %1, off sc0 sc1" :: "v"(d0), "v"(hb0) : "memory");
            asm volatile("global_store_short %0, %1, off sc0 sc1" :: "v"(d1), "v"(hb1) : "memory");
        }
        if (role == 0) {   // Y0(t) sc-stores (consumed cross-XCD by L1)
            u16* y0 = Y0bf + ((size_t)t * BATCH + b_c) * HID + hc0 + c2;
            u16* y1 = y0 + 4;
            asm volatile("global_store_short %0, %1, off sc0 sc1" :: "v"(y0), "v"(hb0) : "memory");
            asm volatile("global_store_short %0, %1, off sc0 sc1" :: "v"(y1), "v"(hb1) : "memory");
        } else {           // final output (plain)
            ys[((size_t)t * BATCH + b_c) * HID + hc0 + c2]     = h_out0;
            ys[((size_t)t * BATCH + b_c) * HID + hc0 + c2 + 4] = h_out1;
        }

        // ---- pipelined barrier: signal, prefetch next x/Y0, wait own domain ----
        bar_signal(ownf, wl, t + 2);     // drains h + Y0 sc-stores first
        if (t < SEQ - 1) {
            if (role == 0) {
                xgemm2_plain(Xbf + (size_t)(t + 1) * BATCH * HID + arow, B0a, B0b, ax0, ax1);
            } else {
                bar_wait128(fa, t + 3);  // L0 finished step t+1 -> Y0(t+1) visible
                xgemm2_sc(Y0bf + (size_t)(t + 1) * BATCH * HID + arow, B0a, B0b, ax0, ax1);
            }
            bar_wait128(ownf, t + 2);
        }
        cur ^= 1;
    }

    hT[(size_t)role * BATCH * HID + (size_t)b_c * HID + hc0 + c2]     = h_out0;
    hT[(size_t)role * BATCH * HID + (size_t)b_c * HID + hc0 + c2 + 4] = h_out1;
    cT[(size_t)role * BATCH * HID + (size_t)b_c * HID + hc0 + c2]     = c_reg0;
    cT[(size_t)role * BATCH * HID + (size_t)b_c * HID + hc0 + c2 + 4] = c_reg1;
}

extern "C" void kernel_launch(void* const* d_in, const int* in_sizes, int n_in,
                              void* d_out, int out_size, void* d_ws, size_t ws_size,
                              hipStream_t stream) {
    const float* x  = (const float*)d_in[0];
    const float* h0 = (const float*)d_in[1];
    const float* c0 = (const float*)d_in[2];
    const float* Wx = (const float*)d_in[3];
    const float* bx = (const float*)d_in[4];
    const float* Wh = (const float*)d_in[5];
    const float* bh = (const float*)d_in[6];
    float* out = (float*)d_out;

    u16* Xbf  = (u16*)d_ws;                                    // 16.78M elems
    u16* Y0bf = Xbf + (size_t)SEQ * BATCH * HID;               // 16.78M elems
    u16* hbuf = Y0bf + (size_t)SEQ * BATCH * HID;              // 2 roles x 2 x B x H
    int* bar  = (int*)(hbuf + (size_t)2 * 2 * BATCH * HID);

    int n4 = (SEQ * BATCH * HID) / 4;
    cvt_f32_bf16<<<dim3(1024), dim3(256), 0, stream>>>(x, Xbf, n4, bar);

    void* args[] = {(void*)&Xbf, (void*)&Y0bf, (void*)&hbuf, (void*)&bar,
                    (void*)&h0, (void*)&c0, (void*)&Wx, (void*)&bx,
                    (void*)&Wh, (void*)&bh, (void*)&out};
    hipError_t err = hipLaunchCooperativeKernel((void*)lstm_coop, dim3(NWG), dim3(NTH),
                                                args, 0, stream);
    if (err != hipSuccess) {
        (void)hipGetLastError();   // 256 x 256t is trivially co-resident (1 WG/CU)
        lstm_coop<<<dim3(NWG), dim3(NTH), 0, stream>>>(Xbf, Y0bf, hbuf, bar,
                                                       h0, c0, Wx, bx, Wh, bh, out);
    }
}

// Round 15
// 2971.312 us; speedup vs baseline: 1.6888x; 1.0205x over previous
//
#include <hip/hip_runtime.h>
#include <hip/hip_bf16.h>

#define SEQ    256
#define BATCH  64
#define HID    1024
#define G4     4096
#define NWG    256
#define NTH    256
#define LDK2   1032   // padded LDS row stride (bf16): 2064B rows

typedef __bf16 bf16x8 __attribute__((ext_vector_type(8)));
typedef float  f32x4  __attribute__((ext_vector_type(4)));
typedef int    i32x2  __attribute__((ext_vector_type(2)));
typedef unsigned short u16;

__device__ __forceinline__ u16 f2bf(float f) {
    unsigned int u = __float_as_uint(f);
    unsigned int r = (u + 0x7fffu + ((u >> 16) & 1u)) >> 16;  // RNE
    return (u16)r;
}
__device__ __forceinline__ float sigmoid_f(float x) {
    x = fminf(fmaxf(x, -30.f), 30.f);
    return 1.f / (1.f + __expf(-x));
}
__device__ __forceinline__ float tanh_f(float x) {
    x = fminf(fmaxf(x, -15.f), 15.f);
    float e2 = __expf(2.f * x);
    return (e2 - 1.f) / (e2 + 1.f);
}

// ---------------- prep: fp32->bf16 for x; zero flags ----------------
__global__ void cvt_f32_bf16(const float* __restrict__ in, u16* __restrict__ out, int n4,
                             int* __restrict__ bar) {
    int idx = blockIdx.x * blockDim.x + threadIdx.x;
    if (idx < 1024)
        __hip_atomic_store(bar + idx, 0, __ATOMIC_RELAXED, __HIP_MEMORY_SCOPE_AGENT);
    int stride = gridDim.x * blockDim.x;
    const float4* in4 = (const float4*)in;
    ushort4* out4 = (ushort4*)out;
    for (int i = idx; i < n4; i += stride) {
        float4 v = in4[i];
        ushort4 o;
        o.x = f2bf(v.x); o.y = f2bf(v.y); o.z = f2bf(v.z); o.w = f2bf(v.w);
        out4[i] = o;
    }
}

// ---- domain flag barrier (128 WGs/domain). Signal: sc-store own flag.
// Wait: wave 0 polls 128 flags, 2 per lane, via sc dwordx2. Monotonic fids.
__device__ __forceinline__ void bar_signal(int* f, int idx, int fid) {
    asm volatile("s_waitcnt vmcnt(0)" ::: "memory");  // drain h/Y0 sc-stores to L3
    __syncthreads();                                  // whole WG drained
    if (threadIdx.x == 0)
        __hip_atomic_store(f + idx, fid, __ATOMIC_RELAXED, __HIP_MEMORY_SCOPE_AGENT);
}
__device__ __forceinline__ void bar_wait128(const int* f, int fid) {
    if (threadIdx.x < 64) {
        const int* p = f + threadIdx.x * 2;
        for (;;) {
            i32x2 v;
            asm volatile("global_load_dwordx2 %0, %1, off sc0 sc1" : "=v"(v) : "v"(p));
            asm volatile("s_waitcnt vmcnt(0)" ::: "memory");
            if (__all(v[0] >= fid && v[1] >= fid)) break;
        }
    }
    __syncthreads();
}

#define SCLD(dst, base, OFFS) \
    asm volatile("global_load_dwordx4 %0, %1, off offset:" OFFS " sc0 sc1" \
                 : "=v"(dst) : "v"(base))
#define SCLD32(a, base) do { \
    SCLD(a[ 0],base,   "0"); SCLD(a[ 1],base,  "64"); SCLD(a[ 2],base, "128"); SCLD(a[ 3],base, "192"); \
    SCLD(a[ 4],base, "256"); SCLD(a[ 5],base, "320"); SCLD(a[ 6],base, "384"); SCLD(a[ 7],base, "448"); \
    SCLD(a[ 8],base, "512"); SCLD(a[ 9],base, "576"); SCLD(a[10],base, "640"); SCLD(a[11],base, "704"); \
    SCLD(a[12],base, "768"); SCLD(a[13],base, "832"); SCLD(a[14],base, "896"); SCLD(a[15],base, "960"); \
    SCLD(a[16],base,"1024"); SCLD(a[17],base,"1088"); SCLD(a[18],base,"1152"); SCLD(a[19],base,"1216"); \
    SCLD(a[20],base,"1280"); SCLD(a[21],base,"1344"); SCLD(a[22],base,"1408"); SCLD(a[23],base,"1472"); \
    SCLD(a[24],base,"1536"); SCLD(a[25],base,"1600"); SCLD(a[26],base,"1664"); SCLD(a[27],base,"1728"); \
    SCLD(a[28],base,"1792"); SCLD(a[29],base,"1856"); SCLD(a[30],base,"1920"); SCLD(a[31],base,"1984"); \
} while (0)

// 2-N-tile x-GEMM: A plain (L2), B from LDS. One A-fragment feeds both tiles.
__device__ __forceinline__ void xgemm2_plain(const u16* __restrict__ A,
                                             const u16* Ba, const u16* Bb,
                                             f32x4& r0, f32x4& r1) {
    f32x4 a0 = {0.f,0.f,0.f,0.f}, a1 = {0.f,0.f,0.f,0.f};
    #pragma unroll
    for (int ks = 0; ks < 32; ++ks) {
        bf16x8 a = *(const bf16x8*)(A + ks * 32);
        a0 = __builtin_amdgcn_mfma_f32_16x16x32_bf16(a, *(const bf16x8*)(Ba + ks * 32), a0, 0, 0, 0);
        a1 = __builtin_amdgcn_mfma_f32_16x16x32_bf16(a, *(const bf16x8*)(Bb + ks * 32), a1, 0, 0, 0);
    }
    r0 = a0; r1 = a1;
}
// 2-N-tile x-GEMM with sc-loaded A (Y0 cross-XCD)
__device__ __forceinline__ void xgemm2_sc(const u16* A, const u16* Ba, const u16* Bb,
                                          f32x4& r0, f32x4& r1) {
    bf16x8 xf[32];
    SCLD32(xf, A);
    asm volatile("s_waitcnt vmcnt(0)" ::: "memory");
    __builtin_amdgcn_sched_barrier(0);
    f32x4 a0 = {0.f,0.f,0.f,0.f}, a1 = {0.f,0.f,0.f,0.f};
    #pragma unroll
    for (int ks = 0; ks < 32; ++ks) {
        a0 = __builtin_amdgcn_mfma_f32_16x16x32_bf16(xf[ks], *(const bf16x8*)(Ba + ks * 32), a0, 0, 0, 0);
        a1 = __builtin_amdgcn_mfma_f32_16x16x32_bf16(xf[ks], *(const bf16x8*)(Bb + ks * 32), a1, 0, 0, 0);
    }
    r0 = a0; r1 = a1;
}

// ---------------- layer-pipelined persistent LSTM (R12 champion + 4-chain h-GEMM) ----------------
// role = wg>>7 (layer); wl = wg&127 owns h-cols [8wl, 8wl+8) x 4 gates = 32 gate-rows.
// Wave wv: batch rows [16wv,16wv+16) x all 32 gate-cols (2 MFMA tiles, shared A-frag).
// Cell: thread tid -> row b = tid>>2, cols (tid&3) and (tid&3)+4.
// L1 lags L0 one step; polls L0's flags before sc-loading Y0(t+1). No back-pressure.
__global__ void __launch_bounds__(NTH, 1) lstm_coop(
    const u16* __restrict__ Xbf,   // [SEQ][BATCH][HID] bf16
    u16* __restrict__ Y0bf,        // [SEQ][BATCH][HID] bf16 (L0 out, sc both sides)
    u16* __restrict__ hbuf,        // [2 roles][2][BATCH][HID] bf16 (sc-accessed)
    int* __restrict__ bar,         // fa[128] | fb[128]
    const float* __restrict__ h0,
    const float* __restrict__ c0,
    const float* __restrict__ Wx,  // [2][4096][1024] fp32
    const float* __restrict__ bx,
    const float* __restrict__ Wh,  // [2][4096][1024] fp32
    const float* __restrict__ bh,
    float* __restrict__ out)       // ys | hT | cT
{
    __shared__ u16   WxL[32 * LDK2];
    __shared__ u16   WhL[32 * LDK2];
    __shared__ float biasL[32];
    __shared__ float gbuf[4][16][33];   // [wave][local row][gate-col j 0..31], padded

    const int wg   = blockIdx.x;
    const int role = wg >> 7;
    const int wl   = wg & 127;
    const int hc0  = wl * 8;
    const int tid  = threadIdx.x;
    const int wv   = tid >> 6;
    const int lane = tid & 63;
    const int fr   = lane & 15;
    const int fg   = lane >> 4;
    const int b_c  = tid >> 2;       // cell batch row 0..63
    const int c2   = tid & 3;        // cell cols c2, c2+4

    int* fa = bar;
    int* fb = bar + 128;
    int* ownf = role ? fb : fa;

    u16* hbufR = hbuf + (size_t)role * 2 * BATCH * HID;

    float* ys = out;
    float* hT = out + (size_t)SEQ * BATCH * HID;
    float* cT = hT + (size_t)2 * BATCH * HID;

    // ---- stage Wx/Wh slices (32 gate-rows each) into LDS, fp32->bf16 ----
    for (int j = 0; j < 32; ++j) {
        int gate = j >> 3, jc = j & 7;
        size_t row = (size_t)role * G4 + (size_t)gate * HID + hc0 + jc;
        float4 vx = ((const float4*)(Wx + row * HID))[tid];
        float4 vh = ((const float4*)(Wh + row * HID))[tid];
        ushort4 ox, oh;
        ox.x = f2bf(vx.x); ox.y = f2bf(vx.y); ox.z = f2bf(vx.z); ox.w = f2bf(vx.w);
        oh.x = f2bf(vh.x); oh.y = f2bf(vh.y); oh.z = f2bf(vh.z); oh.w = f2bf(vh.w);
        *(ushort4*)&WxL[j * LDK2 + tid * 4] = ox;
        *(ushort4*)&WhL[j * LDK2 + tid * 4] = oh;
    }
    if (tid < 32) {
        int gate = tid >> 3, jc = tid & 7;
        int row = role * G4 + gate * HID + hc0 + jc;
        biasL[tid] = bx[row] + bh[row];
    }

    // ---- init h (sc-stores, buffer 0) and per-thread c (2 cells) ----
    float c_reg0, c_reg1;
    {
        float hv0 = h0[(size_t)role * BATCH * HID + (size_t)b_c * HID + hc0 + c2];
        float hv1 = h0[(size_t)role * BATCH * HID + (size_t)b_c * HID + hc0 + c2 + 4];
        u16* d0 = hbufR + (size_t)b_c * HID + hc0 + c2;
        u16* d1 = d0 + 4;
        unsigned int v0 = f2bf(hv0), v1 = f2bf(hv1);
        asm volatile("global_store_short %0, %1, off sc0 sc1" :: "v"(d0), "v"(v0) : "memory");
        asm volatile("global_store_short %0, %1, off sc0 sc1" :: "v"(d1), "v"(v1) : "memory");
        c_reg0 = c0[(size_t)role * BATCH * HID + (size_t)b_c * HID + hc0 + c2];
        c_reg1 = c0[(size_t)role * BATCH * HID + (size_t)b_c * HID + hc0 + c2 + 4];
    }

    bar_signal(ownf, wl, 1);
    bar_wait128(ownf, 1);

    const u16* B0a = &WxL[fr * LDK2 + fg * 8];
    const u16* B0b = &WxL[(16 + fr) * LDK2 + fg * 8];
    const u16* B1a = &WhL[fr * LDK2 + fg * 8];
    const u16* B1b = &WhL[(16 + fr) * LDK2 + fg * 8];
    const size_t arow = (size_t)(wv * 16 + fr) * HID + fg * 8;
    const float bias0 = biasL[fr];
    const float bias1 = biasL[16 + fr];

    f32x4 ax0, ax1;
    if (role == 0) {
        xgemm2_plain(Xbf + arow, B0a, B0b, ax0, ax1);
    } else {
        bar_wait128(fa, 2);                       // Y0(0) published
        xgemm2_sc(Y0bf + arow, B0a, B0b, ax0, ax1);
    }

    int cur = 0;
    float h_out0 = 0.f, h_out1 = 0.f;

    for (int t = 0; t < SEQ; ++t) {
        // ---- h-GEMM: 32 sc-loads (one A-frag), 4 independent 16-deep chains ----
        const u16* A1 = hbufR + (size_t)cur * BATCH * HID + arow;
        bf16x8 hf[32];
        SCLD32(hf, A1);
        asm volatile("s_waitcnt vmcnt(0)" ::: "memory");
        __builtin_amdgcn_sched_barrier(0);
        f32x4 acc0 = ax0, acc1 = ax1;
        f32x4 acc0b = {0.f,0.f,0.f,0.f}, acc1b = {0.f,0.f,0.f,0.f};
        #pragma unroll
        for (int ks = 0; ks < 32; ks += 2) {
            bf16x8 a  = hf[ks];
            bf16x8 a2 = hf[ks + 1];
            acc0  = __builtin_amdgcn_mfma_f32_16x16x32_bf16(a,  *(const bf16x8*)(B1a + ks * 32),       acc0,  0, 0, 0);
            acc1  = __builtin_amdgcn_mfma_f32_16x16x32_bf16(a,  *(const bf16x8*)(B1b + ks * 32),       acc1,  0, 0, 0);
            acc0b = __builtin_amdgcn_mfma_f32_16x16x32_bf16(a2, *(const bf16x8*)(B1a + (ks + 1) * 32), acc0b, 0, 0, 0);
            acc1b = __builtin_amdgcn_mfma_f32_16x16x32_bf16(a2, *(const bf16x8*)(B1b + (ks + 1) * 32), acc1b, 0, 0, 0);
        }

        // ---- gates -> gbuf ----
        #pragma unroll
        for (int i = 0; i < 4; ++i) {
            gbuf[wv][fg * 4 + i][fr]      = acc0[i] + acc0b[i] + bias0;
            gbuf[wv][fg * 4 + i][16 + fr] = acc1[i] + acc1b[i] + bias1;
        }
        __syncthreads();

        // ---- cell update (2 cells/thread) ----
        const int bw = b_c >> 4, br = b_c & 15;
        float gi0 = gbuf[bw][br][c2];          float gi1 = gbuf[bw][br][c2 + 4];
        float gf0 = gbuf[bw][br][8 + c2];      float gf1 = gbuf[bw][br][8 + c2 + 4];
        float gg0 = gbuf[bw][br][16 + c2];     float gg1 = gbuf[bw][br][16 + c2 + 4];
        float go0 = gbuf[bw][br][24 + c2];     float go1 = gbuf[bw][br][24 + c2 + 4];
        c_reg0 = sigmoid_f(gf0) * c_reg0 + sigmoid_f(gi0) * tanh_f(gg0);
        h_out0 = sigmoid_f(go0) * tanh_f(c_reg0);
        c_reg1 = sigmoid_f(gf1) * c_reg1 + sigmoid_f(gi1) * tanh_f(gg1);
        h_out1 = sigmoid_f(go1) * tanh_f(c_reg1);

        unsigned int hb0 = f2bf(h_out0), hb1 = f2bf(h_out1);
        {   // h(t+1) sc-stores
            u16* d0 = hbufR + (size_t)(cur ^ 1) * BATCH * HID + (size_t)b_c * HID + hc0 + c2;
            u16* d1 = d0 + 4;
            asm volatile("global_store_short %0, %1, off sc0 sc1" :: "v"(d0), "v"(hb0) : "memory");
            asm volatile("global_store_short %0, %1, off sc0 sc1" :: "v"(d1), "v"(hb1) : "memory");
        }
        if (role == 0) {   // Y0(t) sc-stores (consumed cross-XCD by L1)
            u16* y0 = Y0bf + ((size_t)t * BATCH + b_c) * HID + hc0 + c2;
            u16* y1 = y0 + 4;
            asm volatile("global_store_short %0, %1, off sc0 sc1" :: "v"(y0), "v"(hb0) : "memory");
            asm volatile("global_store_short %0, %1, off sc0 sc1" :: "v"(y1), "v"(hb1) : "memory");
        } else {           // final output (plain)
            ys[((size_t)t * BATCH + b_c) * HID + hc0 + c2]     = h_out0;
            ys[((size_t)t * BATCH + b_c) * HID + hc0 + c2 + 4] = h_out1;
        }

        // ---- pipelined barrier: signal, prefetch next x/Y0, wait own domain ----
        bar_signal(ownf, wl, t + 2);     // drains h + Y0 sc-stores first
        if (t < SEQ - 1) {
            if (role == 0) {
                xgemm2_plain(Xbf + (size_t)(t + 1) * BATCH * HID + arow, B0a, B0b, ax0, ax1);
            } else {
                bar_wait128(fa, t + 3);  // L0 finished step t+1 -> Y0(t+1) visible
                xgemm2_sc(Y0bf + (size_t)(t + 1) * BATCH * HID + arow, B0a, B0b, ax0, ax1);
            }
            bar_wait128(ownf, t + 2);
        }
        cur ^= 1;
    }

    hT[(size_t)role * BATCH * HID + (size_t)b_c * HID + hc0 + c2]     = h_out0;
    hT[(size_t)role * BATCH * HID + (size_t)b_c * HID + hc0 + c2 + 4] = h_out1;
    cT[(size_t)role * BATCH * HID + (size_t)b_c * HID + hc0 + c2]     = c_reg0;
    cT[(size_t)role * BATCH * HID + (size_t)b_c * HID + hc0 + c2 + 4] = c_reg1;
}

extern "C" void kernel_launch(void* const* d_in, const int* in_sizes, int n_in,
                              void* d_out, int out_size, void* d_ws, size_t ws_size,
                              hipStream_t stream) {
    const float* x  = (const float*)d_in[0];
    const float* h0 = (const float*)d_in[1];
    const float* c0 = (const float*)d_in[2];
    const float* Wx = (const float*)d_in[3];
    const float* bx = (const float*)d_in[4];
    const float* Wh = (const float*)d_in[5];
    const float* bh = (const float*)d_in[6];
    float* out = (float*)d_out;

    u16* Xbf  = (u16*)d_ws;                                    // 16.78M elems
    u16* Y0bf = Xbf + (size_t)SEQ * BATCH * HID;               // 16.78M elems
    u16* hbuf = Y0bf + (size_t)SEQ * BATCH * HID;              // 2 roles x 2 x B x H
    int* bar  = (int*)(hbuf + (size_t)2 * 2 * BATCH * HID);

    int n4 = (SEQ * BATCH * HID) / 4;
    cvt_f32_bf16<<<dim3(1024), dim3(256), 0, stream>>>(x, Xbf, n4, bar);

    void* args[] = {(void*)&Xbf, (void*)&Y0bf, (void*)&hbuf, (void*)&bar,
                    (void*)&h0, (void*)&c0, (void*)&Wx, (void*)&bx,
                    (void*)&Wh, (void*)&bh, (void*)&out};
    hipError_t err = hipLaunchCooperativeKernel((void*)lstm_coop, dim3(NWG), dim3(NTH),
                                                args, 0, stream);
    if (err != hipSuccess) {
        (void)hipGetLastError();   // 256 x 256t is trivially co-resident (1 WG/CU)
        lstm_coop<<<dim3(NWG), dim3(NTH), 0, stream>>>(Xbf, Y0bf, hbuf, bar,
                                                       h0, c0, Wx, bx, Wh, bh, out);
    }
}

// Round 16
// 2959.508 us; speedup vs baseline: 1.6956x; 1.0040x over previous
//
#include <hip/hip_runtime.h>
#include <hip/hip_bf16.h>

#define SEQ    256
#define BATCH  64
#define HID    1024
#define G4     4096
#define NWG    256
#define NTH    256
#define LDK2   1032   // padded LDS row stride (bf16): 2064B rows

typedef __bf16 bf16x8 __attribute__((ext_vector_type(8)));
typedef float  f32x4  __attribute__((ext_vector_type(4)));
typedef int    i32x2  __attribute__((ext_vector_type(2)));
typedef unsigned short u16;

__device__ __forceinline__ u16 f2bf(float f) {
    unsigned int u = __float_as_uint(f);
    unsigned int r = (u + 0x7fffu + ((u >> 16) & 1u)) >> 16;  // RNE
    return (u16)r;
}
__device__ __forceinline__ float sigmoid_f(float x) {
    x = fminf(fmaxf(x, -30.f), 30.f);
    return 1.f / (1.f + __expf(-x));
}
__device__ __forceinline__ float tanh_f(float x) {
    x = fminf(fmaxf(x, -15.f), 15.f);
    float e2 = __expf(2.f * x);
    return (e2 - 1.f) / (e2 + 1.f);
}

// ---------------- prep: fp32->bf16 for x; zero flags ----------------
__global__ void cvt_f32_bf16(const float* __restrict__ in, u16* __restrict__ out, int n4,
                             int* __restrict__ bar) {
    int idx = blockIdx.x * blockDim.x + threadIdx.x;
    if (idx < 1024)
        __hip_atomic_store(bar + idx, 0, __ATOMIC_RELAXED, __HIP_MEMORY_SCOPE_AGENT);
    int stride = gridDim.x * blockDim.x;
    const float4* in4 = (const float4*)in;
    ushort4* out4 = (ushort4*)out;
    for (int i = idx; i < n4; i += stride) {
        float4 v = in4[i];
        ushort4 o;
        o.x = f2bf(v.x); o.y = f2bf(v.y); o.z = f2bf(v.z); o.w = f2bf(v.w);
        out4[i] = o;
    }
}

// ---- domain flag barrier (128 WGs/domain). Signal: sc-store own flag.
// Wait: wave 0 polls 128 flags, 2 per lane, via sc dwordx2. Monotonic fids.
__device__ __forceinline__ void bar_signal(int* f, int idx, int fid) {
    asm volatile("s_waitcnt vmcnt(0)" ::: "memory");  // drain h/Y0 sc-stores to L3
    __syncthreads();                                  // whole WG drained
    if (threadIdx.x == 0)
        __hip_atomic_store(f + idx, fid, __ATOMIC_RELAXED, __HIP_MEMORY_SCOPE_AGENT);
}
__device__ __forceinline__ void bar_wait128(const int* f, int fid) {
    if (threadIdx.x < 64) {
        const int* p = f + threadIdx.x * 2;
        for (;;) {
            i32x2 v;
            asm volatile("global_load_dwordx2 %0, %1, off sc0 sc1" : "=v"(v) : "v"(p));
            asm volatile("s_waitcnt vmcnt(0)" ::: "memory");
            if (__all(v[0] >= fid && v[1] >= fid)) break;
        }
    }
    __syncthreads();
}

#define SCLD(dst, base, OFFS) \
    asm volatile("global_load_dwordx4 %0, %1, off offset:" OFFS " sc0 sc1" \
                 : "=v"(dst) : "v"(base))
#define SCLD32(a, base) do { \
    SCLD(a[ 0],base,   "0"); SCLD(a[ 1],base,  "64"); SCLD(a[ 2],base, "128"); SCLD(a[ 3],base, "192"); \
    SCLD(a[ 4],base, "256"); SCLD(a[ 5],base, "320"); SCLD(a[ 6],base, "384"); SCLD(a[ 7],base, "448"); \
    SCLD(a[ 8],base, "512"); SCLD(a[ 9],base, "576"); SCLD(a[10],base, "640"); SCLD(a[11],base, "704"); \
    SCLD(a[12],base, "768"); SCLD(a[13],base, "832"); SCLD(a[14],base, "896"); SCLD(a[15],base, "960"); \
    SCLD(a[16],base,"1024"); SCLD(a[17],base,"1088"); SCLD(a[18],base,"1152"); SCLD(a[19],base,"1216"); \
    SCLD(a[20],base,"1280"); SCLD(a[21],base,"1344"); SCLD(a[22],base,"1408"); SCLD(a[23],base,"1472"); \
    SCLD(a[24],base,"1536"); SCLD(a[25],base,"1600"); SCLD(a[26],base,"1664"); SCLD(a[27],base,"1728"); \
    SCLD(a[28],base,"1792"); SCLD(a[29],base,"1856"); SCLD(a[30],base,"1920"); SCLD(a[31],base,"1984"); \
} while (0)

// 2-N-tile x-GEMM: A plain (L2), B from LDS. One A-fragment feeds both tiles.
__device__ __forceinline__ void xgemm2_plain(const u16* __restrict__ A,
                                             const u16* Ba, const u16* Bb,
                                             f32x4& r0, f32x4& r1) {
    f32x4 a0 = {0.f,0.f,0.f,0.f}, a1 = {0.f,0.f,0.f,0.f};
    #pragma unroll
    for (int ks = 0; ks < 32; ++ks) {
        bf16x8 a = *(const bf16x8*)(A + ks * 32);
        a0 = __builtin_amdgcn_mfma_f32_16x16x32_bf16(a, *(const bf16x8*)(Ba + ks * 32), a0, 0, 0, 0);
        a1 = __builtin_amdgcn_mfma_f32_16x16x32_bf16(a, *(const bf16x8*)(Bb + ks * 32), a1, 0, 0, 0);
    }
    r0 = a0; r1 = a1;
}
// 2-N-tile x-GEMM with sc-loaded A (Y0 cross-XCD)
__device__ __forceinline__ void xgemm2_sc(const u16* A, const u16* Ba, const u16* Bb,
                                          f32x4& r0, f32x4& r1) {
    bf16x8 xf[32];
    SCLD32(xf, A);
    asm volatile("s_waitcnt vmcnt(0)" ::: "memory");
    __builtin_amdgcn_sched_barrier(0);
    f32x4 a0 = {0.f,0.f,0.f,0.f}, a1 = {0.f,0.f,0.f,0.f};
    #pragma unroll
    for (int ks = 0; ks < 32; ++ks) {
        a0 = __builtin_amdgcn_mfma_f32_16x16x32_bf16(xf[ks], *(const bf16x8*)(Ba + ks * 32), a0, 0, 0, 0);
        a1 = __builtin_amdgcn_mfma_f32_16x16x32_bf16(xf[ks], *(const bf16x8*)(Bb + ks * 32), a1, 0, 0, 0);
    }
    r0 = a0; r1 = a1;
}

// ---------------- layer-pipelined persistent LSTM (R15 + intra-wave exchange, setprio) ----------------
// role = wg>>7 (layer); wl = wg&127 owns h-cols [8wl, 8wl+8) x 4 gates = 32 gate-rows.
// Wave wv: batch rows [16wv,16wv+16) x all 32 gate-cols (2 MFMA tiles, shared A-frag).
// Cell: thread tid -> row b = tid>>2, cols (tid&3) and (tid&3)+4.
// NOTE: gate exchange (gbuf) is INTRA-WAVE (writer wave wv == reader wave tid>>6),
// so no __syncthreads() between write and read — per-wave LDS ops are in-order.
__global__ void __launch_bounds__(NTH, 1) lstm_coop(
    const u16* __restrict__ Xbf,   // [SEQ][BATCH][HID] bf16
    u16* __restrict__ Y0bf,        // [SEQ][BATCH][HID] bf16 (L0 out, sc both sides)
    u16* __restrict__ hbuf,        // [2 roles][2][BATCH][HID] bf16 (sc-accessed)
    int* __restrict__ bar,         // fa[128] | fb[128]
    const float* __restrict__ h0,
    const float* __restrict__ c0,
    const float* __restrict__ Wx,  // [2][4096][1024] fp32
    const float* __restrict__ bx,
    const float* __restrict__ Wh,  // [2][4096][1024] fp32
    const float* __restrict__ bh,
    float* __restrict__ out)       // ys | hT | cT
{
    __shared__ u16   WxL[32 * LDK2];
    __shared__ u16   WhL[32 * LDK2];
    __shared__ float biasL[32];
    __shared__ float gbuf[4][16][33];   // [wave][local row][gate-col j 0..31], padded

    const int wg   = blockIdx.x;
    const int role = wg >> 7;
    const int wl   = wg & 127;
    const int hc0  = wl * 8;
    const int tid  = threadIdx.x;
    const int wv   = tid >> 6;
    const int lane = tid & 63;
    const int fr   = lane & 15;
    const int fg   = lane >> 4;
    const int b_c  = tid >> 2;       // cell batch row 0..63
    const int c2   = tid & 3;        // cell cols c2, c2+4

    int* fa = bar;
    int* fb = bar + 128;
    int* ownf = role ? fb : fa;

    u16* hbufR = hbuf + (size_t)role * 2 * BATCH * HID;

    float* ys = out;
    float* hT = out + (size_t)SEQ * BATCH * HID;
    float* cT = hT + (size_t)2 * BATCH * HID;

    // ---- stage Wx/Wh slices (32 gate-rows each) into LDS, fp32->bf16 ----
    for (int j = 0; j < 32; ++j) {
        int gate = j >> 3, jc = j & 7;
        size_t row = (size_t)role * G4 + (size_t)gate * HID + hc0 + jc;
        float4 vx = ((const float4*)(Wx + row * HID))[tid];
        float4 vh = ((const float4*)(Wh + row * HID))[tid];
        ushort4 ox, oh;
        ox.x = f2bf(vx.x); ox.y = f2bf(vx.y); ox.z = f2bf(vx.z); ox.w = f2bf(vx.w);
        oh.x = f2bf(vh.x); oh.y = f2bf(vh.y); oh.z = f2bf(vh.z); oh.w = f2bf(vh.w);
        *(ushort4*)&WxL[j * LDK2 + tid * 4] = ox;
        *(ushort4*)&WhL[j * LDK2 + tid * 4] = oh;
    }
    if (tid < 32) {
        int gate = tid >> 3, jc = tid & 7;
        int row = role * G4 + gate * HID + hc0 + jc;
        biasL[tid] = bx[row] + bh[row];
    }

    // ---- init h (sc-stores, buffer 0) and per-thread c (2 cells) ----
    float c_reg0, c_reg1;
    {
        float hv0 = h0[(size_t)role * BATCH * HID + (size_t)b_c * HID + hc0 + c2];
        float hv1 = h0[(size_t)role * BATCH * HID + (size_t)b_c * HID + hc0 + c2 + 4];
        u16* d0 = hbufR + (size_t)b_c * HID + hc0 + c2;
        u16* d1 = d0 + 4;
        unsigned int v0 = f2bf(hv0), v1 = f2bf(hv1);
        asm volatile("global_store_short %0, %1, off sc0 sc1" :: "v"(d0), "v"(v0) : "memory");
        asm volatile("global_store_short %0, %1, off sc0 sc1" :: "v"(d1), "v"(v1) : "memory");
        c_reg0 = c0[(size_t)role * BATCH * HID + (size_t)b_c * HID + hc0 + c2];
        c_reg1 = c0[(size_t)role * BATCH * HID + (size_t)b_c * HID + hc0 + c2 + 4];
    }

    bar_signal(ownf, wl, 1);
    bar_wait128(ownf, 1);

    const u16* B0a = &WxL[fr * LDK2 + fg * 8];
    const u16* B0b = &WxL[(16 + fr) * LDK2 + fg * 8];
    const u16* B1a = &WhL[fr * LDK2 + fg * 8];
    const u16* B1b = &WhL[(16 + fr) * LDK2 + fg * 8];
    const size_t arow = (size_t)(wv * 16 + fr) * HID + fg * 8;
    const float bias0 = biasL[fr];
    const float bias1 = biasL[16 + fr];

    f32x4 ax0, ax1;
    if (role == 0) {
        xgemm2_plain(Xbf + arow, B0a, B0b, ax0, ax1);
    } else {
        bar_wait128(fa, 2);                       // Y0(0) published
        xgemm2_sc(Y0bf + arow, B0a, B0b, ax0, ax1);
    }

    int cur = 0;
    float h_out0 = 0.f, h_out1 = 0.f;

    for (int t = 0; t < SEQ; ++t) {
        // ---- h-GEMM: 32 sc-loads (one A-frag), 4 independent 16-deep chains ----
        const u16* A1 = hbufR + (size_t)cur * BATCH * HID + arow;
        bf16x8 hf[32];
        SCLD32(hf, A1);
        asm volatile("s_waitcnt vmcnt(0)" ::: "memory");
        __builtin_amdgcn_sched_barrier(0);
        __builtin_amdgcn_s_setprio(1);
        f32x4 acc0 = ax0, acc1 = ax1;
        f32x4 acc0b = {0.f,0.f,0.f,0.f}, acc1b = {0.f,0.f,0.f,0.f};
        #pragma unroll
        for (int ks = 0; ks < 32; ks += 2) {
            bf16x8 a  = hf[ks];
            bf16x8 a2 = hf[ks + 1];
            acc0  = __builtin_amdgcn_mfma_f32_16x16x32_bf16(a,  *(const bf16x8*)(B1a + ks * 32),       acc0,  0, 0, 0);
            acc1  = __builtin_amdgcn_mfma_f32_16x16x32_bf16(a,  *(const bf16x8*)(B1b + ks * 32),       acc1,  0, 0, 0);
            acc0b = __builtin_amdgcn_mfma_f32_16x16x32_bf16(a2, *(const bf16x8*)(B1a + (ks + 1) * 32), acc0b, 0, 0, 0);
            acc1b = __builtin_amdgcn_mfma_f32_16x16x32_bf16(a2, *(const bf16x8*)(B1b + (ks + 1) * 32), acc1b, 0, 0, 0);
        }
        __builtin_amdgcn_s_setprio(0);

        // ---- gates -> gbuf (INTRA-WAVE exchange; no syncthreads needed) ----
        #pragma unroll
        for (int i = 0; i < 4; ++i) {
            gbuf[wv][fg * 4 + i][fr]      = acc0[i] + acc0b[i] + bias0;
            gbuf[wv][fg * 4 + i][16 + fr] = acc1[i] + acc1b[i] + bias1;
        }

        // ---- cell update (2 cells/thread; reads own wave's gbuf slab) ----
        const int bw = b_c >> 4, br = b_c & 15;
        float gi0 = gbuf[bw][br][c2];          float gi1 = gbuf[bw][br][c2 + 4];
        float gf0 = gbuf[bw][br][8 + c2];      float gf1 = gbuf[bw][br][8 + c2 + 4];
        float gg0 = gbuf[bw][br][16 + c2];     float gg1 = gbuf[bw][br][16 + c2 + 4];
        float go0 = gbuf[bw][br][24 + c2];     float go1 = gbuf[bw][br][24 + c2 + 4];
        c_reg0 = sigmoid_f(gf0) * c_reg0 + sigmoid_f(gi0) * tanh_f(gg0);
        h_out0 = sigmoid_f(go0) * tanh_f(c_reg0);
        c_reg1 = sigmoid_f(gf1) * c_reg1 + sigmoid_f(gi1) * tanh_f(gg1);
        h_out1 = sigmoid_f(go1) * tanh_f(c_reg1);

        unsigned int hb0 = f2bf(h_out0), hb1 = f2bf(h_out1);
        {   // h(t+1) sc-stores
            u16* d0 = hbufR + (size_t)(cur ^ 1) * BATCH * HID + (size_t)b_c * HID + hc0 + c2;
            u16* d1 = d0 + 4;
            asm volatile("global_store_short %0, %1, off sc0 sc1" :: "v"(d0), "v"(hb0) : "memory");
            asm volatile("global_store_short %0, %1, off sc0 sc1" :: "v"(d1), "v"(hb1) : "memory");
        }
        if (role == 0) {   // Y0(t) sc-stores (consumed cross-XCD by L1)
            u16* y0 = Y0bf + ((size_t)t * BATCH + b_c) * HID + hc0 + c2;
            u16* y1 = y0 + 4;
            asm volatile("global_store_short %0, %1, off sc0 sc1" :: "v"(y0), "v"(hb0) : "memory");
            asm volatile("global_store_short %0, %1, off sc0 sc1" :: "v"(y1), "v"(hb1) : "memory");
        } else {           // final output (plain)
            ys[((size_t)t * BATCH + b_c) * HID + hc0 + c2]     = h_out0;
            ys[((size_t)t * BATCH + b_c) * HID + hc0 + c2 + 4] = h_out1;
        }

        // ---- pipelined barrier: signal, prefetch next x/Y0, wait own domain ----
        bar_signal(ownf, wl, t + 2);     // drains h + Y0 sc-stores first
        if (t < SEQ - 1) {
            if (role == 0) {
                xgemm2_plain(Xbf + (size_t)(t + 1) * BATCH * HID + arow, B0a, B0b, ax0, ax1);
            } else {
                bar_wait128(fa, t + 3);  // L0 finished step t+1 -> Y0(t+1) visible
                xgemm2_sc(Y0bf + (size_t)(t + 1) * BATCH * HID + arow, B0a, B0b, ax0, ax1);
            }
            bar_wait128(ownf, t + 2);
        }
        cur ^= 1;
    }

    hT[(size_t)role * BATCH * HID + (size_t)b_c * HID + hc0 + c2]     = h_out0;
    hT[(size_t)role * BATCH * HID + (size_t)b_c * HID + hc0 + c2 + 4] = h_out1;
    cT[(size_t)role * BATCH * HID + (size_t)b_c * HID + hc0 + c2]     = c_reg0;
    cT[(size_t)role * BATCH * HID + (size_t)b_c * HID + hc0 + c2 + 4] = c_reg1;
}

extern "C" void kernel_launch(void* const* d_in, const int* in_sizes, int n_in,
                              void* d_out, int out_size, void* d_ws, size_t ws_size,
                              hipStream_t stream) {
    const float* x  = (const float*)d_in[0];
    const float* h0 = (const float*)d_in[1];
    const float* c0 = (const float*)d_in[2];
    const float* Wx = (const float*)d_in[3];
    const float* bx = (const float*)d_in[4];
    const float* Wh = (const float*)d_in[5];
    const float* bh = (const float*)d_in[6];
    float* out = (float*)d_out;

    u16* Xbf  = (u16*)d_ws;                                    // 16.78M elems
    u16* Y0bf = Xbf + (size_t)SEQ * BATCH * HID;               // 16.78M elems
    u16* hbuf = Y0bf + (size_t)SEQ * BATCH * HID;              // 2 roles x 2 x B x H
    int* bar  = (int*)(hbuf + (size_t)2 * 2 * BATCH * HID);

    int n4 = (SEQ * BATCH * HID) / 4;
    cvt_f32_bf16<<<dim3(1024), dim3(256), 0, stream>>>(x, Xbf, n4, bar);

    void* args[] = {(void*)&Xbf, (void*)&Y0bf, (void*)&hbuf, (void*)&bar,
                    (void*)&h0, (void*)&c0, (void*)&Wx, (void*)&bx,
                    (void*)&Wh, (void*)&bh, (void*)&out};
    hipError_t err = hipLaunchCooperativeKernel((void*)lstm_coop, dim3(NWG), dim3(NTH),
                                                args, 0, stream);
    if (err != hipSuccess) {
        (void)hipGetLastError();   // 256 x 256t is trivially co-resident (1 WG/CU)
        lstm_coop<<<dim3(NWG), dim3(NTH), 0, stream>>>(Xbf, Y0bf, hbuf, bar,
                                                       h0, c0, Wx, bx, Wh, bh, out);
    }
}